// Round 7
// baseline (576.368 us; speedup 1.0000x reference)
//
#include <hip/hip_runtime.h>

// VQ-VAE quantizer via MFMA: x[B=128,C=256,H=32,W=32] f32, e[K=512,C=256] f32.
// out[b,c,hw] = e[argmin_k ||z - e_k||^2][c].
//
// R7: ONE-term bf16 MFMA main pass (score_k ~= ||e_k||^2 - 2 zh.eh), error
// sigma_pair ~= 0.07; rows with top-2 gap < EPS=0.6 (~8.5 sigma) re-resolved
// exactly in fp64. This shrinks A-fragments 128->64 VGPRs (R4-R6 were
// register-pressure-bound: VGPR_Count 124 < A-frags alone), MFMA/iter 48->16,
// LDS reads/iter 16->8, and allows 3 waves/SIMD.

typedef __attribute__((ext_vector_type(8))) short bf16x8;
typedef __attribute__((ext_vector_type(4))) float f32x4;

constexpr int K_EMB = 512;
constexpr int C_DIM = 256;
constexpr int HW    = 1024;
constexpr float EPS_GAP = 0.6f;

// ws layout (bytes)
constexpr size_t WS_EBIAS = 64;                    // f32[512]
constexpr size_t WS_EH    = 4096;                  // bf16 bits [512][256] = 256KB
constexpr size_t WS_WORK  = WS_EH + 262144;        // worklist int[]

// LDS: 3 x 8KB e-tile buffers | ebias f32[512] | idx int[128]
constexpr int LDS_TILES = 24576;
constexpr int LDS_EB    = LDS_TILES;           // +2048
constexpr int LDS_IDX   = LDS_TILES + 2048;    // +512 -> 27136 total

__device__ __forceinline__ unsigned short f2bf(float f) {
    unsigned u = __float_as_uint(f);
    return (unsigned short)((u + 0x7FFFu + ((u >> 16) & 1u)) >> 16);
}

// ---- prep: e -> eH bf16 plane + exact ebias, zero job counter ----
__global__ __launch_bounds__(256) void prep_e(const float* __restrict__ e,
                                              unsigned short* __restrict__ eH,
                                              float* __restrict__ ebias,
                                              int* __restrict__ count) {
    const int k = blockIdx.x, c = threadIdx.x;
    if (k == 0 && c == 0) *count = 0;
    float v = e[(size_t)k * C_DIM + c];
    eH[(size_t)k * C_DIM + c] = f2bf(v);

    __shared__ double red[256];
    red[c] = (double)v * (double)v;
    __syncthreads();
    for (int s = 128; s > 0; s >>= 1) {
        if (c < s) red[c] += red[c + s];
        __syncthreads();
    }
    if (c == 0) ebias[k] = (float)red[0];
}

// ---- stage one 16-code e-tile (8KB) into LDS at bufoff ----
// global_load_lds: wave-uniform LDS base, lane*16 contiguous. Bank-conflict
// swizzle (byte ^= (row&15)<<4) applied on the GLOBAL source address
// (both-sides-or-neither); readers apply the same XOR. (R4-R6 verified.)
__device__ __forceinline__ void stage_tile(char* smem, int bufoff, int nt, int w, int lane,
                                           const unsigned short* eH) {
#pragma unroll
    for (int s = 0; s < 2; ++s) {
        int q = w * 2 + s;            // 0..7 across the block (1KB chunks)
        int row = q * 2 + (lane >> 5);
        int co  = (lane & 31) * 16;   // byte offset within 512B row
        const unsigned short* src = eH
            + ((size_t)(nt * 16 + row)) * C_DIM + ((co ^ ((row & 15) << 4)) >> 1);
        char* dst = smem + bufoff + q * 1024;  // wave-uniform
        __builtin_amdgcn_global_load_lds(
            (const __attribute__((address_space(1))) unsigned int*)src,
            (__attribute__((address_space(3))) unsigned int*)dst, 16, 0, 0);
    }
}

// ---- main: 1-term GEMM + in-register argmin + fused output gather ----
__global__ __launch_bounds__(256, 3) void vq_mfma(const float* __restrict__ x,
                                                  const unsigned short* __restrict__ eH,
                                                  const float* __restrict__ ebias,
                                                  const float* __restrict__ e,
                                                  float* __restrict__ out,
                                                  int* __restrict__ count,
                                                  int* __restrict__ worklist,
                                                  int maxjobs) {
    __shared__ __align__(16) char smem[LDS_IDX + 512];
    float* eb_lds = (float*)(smem + LDS_EB);
    int* idx_lds  = (int*)(smem + LDS_IDX);
    const int t = threadIdx.x, lane = t & 63, w = t >> 6;
    const int b = blockIdx.x >> 3;
    const int hw0 = (blockIdx.x & 7) << 7;
    const float* xb = x + (size_t)b * C_DIM * HW;

    // ebias -> LDS (consumed pre-loop; published by the nt=0 barrier)
    eb_lds[t]       = ebias[t];
    eb_lds[t + 256] = ebias[t + 256];

    // prefetch e-tiles 0,1 (max lead: issued before A-build)
    stage_tile(smem, 0,    0, w, lane, eH);
    stage_tile(smem, 8192, 1, w, lane, eH);

    // A fragments (bf16 hi plane only): lane holds A[m=lane&15][k=8*(lane>>4)+j]
    bf16x8 Ah[2][8];
#pragma unroll
    for (int mf = 0; mf < 2; ++mf) {
        const int hw = hw0 + w * 32 + mf * 16 + (lane & 15);
#pragma unroll
        for (int cs = 0; cs < 8; ++cs) {
#pragma unroll
            for (int j = 0; j < 8; ++j) {
                int c = cs * 32 + ((lane >> 4) << 3) + j;
                Ah[mf][cs][j] = (short)f2bf(xb[(size_t)c * HW + hw]);
            }
        }
    }

    float best[8], second[8];
    int bidx[8];
#pragma unroll
    for (int s = 0; s < 8; ++s) { best[s] = 1e30f; second[s] = 1e30f; bidx[s] = 0; }

    // per-lane swizzled LDS read base: row = lane&15 (code), co = (lane>>4)*16
    const int bro = (lane & 15) * 512 + ((((lane >> 4) << 4)) ^ ((lane & 15) << 4));

    // eb_lds ds_writes drained; nt=0 barrier publishes across waves
    asm volatile("s_waitcnt lgkmcnt(0)" ::: "memory");

    int cur = 0;
#pragma unroll 1
    for (int nt = 0; nt < 32; ++nt) {
        // tile nt's 2 loads/wave complete; tile nt+1's 2 may stay in flight
        if (nt == 31) asm volatile("s_waitcnt vmcnt(0)" ::: "memory");
        else          asm volatile("s_waitcnt vmcnt(2)" ::: "memory");
        __builtin_amdgcn_s_barrier();
        asm volatile("" ::: "memory");

        // stage tile nt+2 into the buffer whose reads finished in iter nt-1
        if (nt < 30) {
            int nb = cur + 16384; if (nb >= LDS_TILES) nb -= LDS_TILES;
            stage_tile(smem, nb, nt + 2, w, lane, eH);
        }

        const char* base = smem + cur;
        f32x4 a0 = {0,0,0,0}, a1 = {0,0,0,0};
#pragma unroll
        for (int cs = 0; cs < 8; ++cs) {
            bf16x8 Bh = *reinterpret_cast<const bf16x8*>(base + (bro ^ (cs << 6)));
            a0 = __builtin_amdgcn_mfma_f32_16x16x32_bf16(Ah[0][cs], Bh, a0, 0, 0, 0);
            a1 = __builtin_amdgcn_mfma_f32_16x16x32_bf16(Ah[1][cs], Bh, a1, 0, 0, 0);
        }

        const int code = nt * 16 + (lane & 15);
        const float eb = eb_lds[code];
#pragma unroll
        for (int mf = 0; mf < 2; ++mf) {
#pragma unroll
            for (int r = 0; r < 4; ++r) {
                float sc = fmaf(-2.f, (mf ? a1[r] : a0[r]), eb);
                int slot = mf * 4 + r;
                if (sc < best[slot]) { second[slot] = best[slot]; best[slot] = sc; bidx[slot] = code; }
                else second[slot] = fminf(second[slot], sc);
            }
        }

        cur += 8192; if (cur == LDS_TILES) cur = 0;
    }

    // butterfly argmin over the 16 col-lanes (true top-2, first-idx ties)
#pragma unroll
    for (int m = 1; m < 16; m <<= 1) {
#pragma unroll
        for (int s = 0; s < 8; ++s) {
            float ob = __shfl_xor(best[s], m);
            float os = __shfl_xor(second[s], m);
            int   oi = __shfl_xor(bidx[s], m);
            bool take = (ob < best[s]) || (ob == best[s] && oi < bidx[s]);
            float ns = take ? fminf(best[s], os) : fminf(second[s], ob);
            if (take) { best[s] = ob; bidx[s] = oi; }
            second[s] = ns;
        }
    }

    if ((lane & 15) == 0) {
#pragma unroll
        for (int s = 0; s < 8; ++s) {
            int row_local = (s >> 2) * 16 + ((lane >> 4) << 2) + (s & 3);
            int r = w * 32 + row_local;
            idx_lds[r] = bidx[s];
            if (second[s] - best[s] < EPS_GAP) {
                int sl = atomicAdd(count, 1);
                if (sl < maxjobs) worklist[sl] = blockIdx.x * 128 + r;
            }
        }
    }
    __syncthreads();

    // fused gather: out[b,c,hw] = e[idx[j]][c]; float4 gathers from L2,
    // coalesced stores (lanes = consecutive j).
    {
        const int j = t & 127;
        const int half = t >> 7;
        const int code = idx_lds[j];
        const float4* e4 = reinterpret_cast<const float4*>(e);
        float* ob = out + (size_t)b * C_DIM * HW + hw0 + j;
#pragma unroll
        for (int i = 0; i < 32; ++i) {
            int c4 = half * 32 + i;
            float4 v = e4[(size_t)code * 64 + c4];
            ob[(size_t)(c4 * 4 + 0) * HW] = v.x;
            ob[(size_t)(c4 * 4 + 1) * HW] = v.y;
            ob[(size_t)(c4 * 4 + 2) * HW] = v.z;
            ob[(size_t)(c4 * 4 + 3) * HW] = v.w;
        }
    }
}

// ---- refine: exact fp64 argmin for flagged rows, rewrite out row ----
__global__ __launch_bounds__(64) void refine_kernel(const float* __restrict__ x,
                                                    const float* __restrict__ e,
                                                    float* __restrict__ out,
                                                    const int* __restrict__ worklist,
                                                    const int* __restrict__ count,
                                                    int maxjobs) {
    int njobs = *count;
    if (njobs > maxjobs) njobs = maxjobs;
    const int lane = threadIdx.x;

    for (int job = blockIdx.x; job < njobs; job += gridDim.x) {
        const int row = worklist[job];
        const int b = row >> 10;
        const int hw = row & (HW - 1);
        const float* xb = x + (size_t)b * C_DIM * HW + hw;

        double bestd = 1e300;
        int besti = K_EMB;
        for (int k = lane; k < K_EMB; k += 64) {
            const float* er = e + (size_t)k * C_DIM;
            double d = 0.0;
            for (int c = 0; c < C_DIM; ++c) {
                double diff = (double)xb[(size_t)c * HW] - (double)er[c];
                d = fma(diff, diff, d);
            }
            if (d < bestd || (d == bestd && k < besti)) { bestd = d; besti = k; }
        }
        for (int off = 32; off > 0; off >>= 1) {
            double od = __shfl_down(bestd, off);
            int    oi = __shfl_down(besti, off);
            if (od < bestd || (od == bestd && oi < besti)) { bestd = od; besti = oi; }
        }
        besti = __shfl(besti, 0);

        const float4 v = reinterpret_cast<const float4*>(e + (size_t)besti * C_DIM)[lane];
        float* ob = out + (size_t)b * C_DIM * HW + hw;
        ob[(size_t)(lane * 4 + 0) * HW] = v.x;
        ob[(size_t)(lane * 4 + 1) * HW] = v.y;
        ob[(size_t)(lane * 4 + 2) * HW] = v.z;
        ob[(size_t)(lane * 4 + 3) * HW] = v.w;
    }
}

extern "C" void kernel_launch(void* const* d_in, const int* in_sizes, int n_in,
                              void* d_out, int out_size, void* d_ws, size_t ws_size,
                              hipStream_t stream) {
    const float* x = (const float*)d_in[0];
    const float* e = (const float*)d_in[1];
    float* out = (float*)d_out;

    char* ws = (char*)d_ws;
    int* count = (int*)ws;
    float* ebias = (float*)(ws + WS_EBIAS);
    unsigned short* eH = (unsigned short*)(ws + WS_EH);
    int* worklist = (int*)(ws + WS_WORK);
    int maxjobs = 0;
    if (ws_size > WS_WORK + 4) {
        size_t avail = (ws_size - WS_WORK) / 4;
        maxjobs = (int)(avail > 65536 ? 65536 : avail);
    }

    const int B = in_sizes[0] / (C_DIM * HW);

    hipLaunchKernelGGL(prep_e, dim3(K_EMB), dim3(256), 0, stream, e, eH, ebias, count);
    hipLaunchKernelGGL(vq_mfma, dim3(B * 8), dim3(256), 0, stream,
                       x, eH, ebias, e, out, count, worklist, maxjobs);
    hipLaunchKernelGGL(refine_kernel, dim3(2048), dim3(64), 0, stream,
                       x, e, out, worklist, count, maxjobs);
}

// Round 8
// 382.468 us; speedup vs baseline: 1.5070x; 1.5070x over previous
//
#include <hip/hip_runtime.h>

// VQ-VAE quantizer via MFMA: x[B=128,C=256,H=32,W=32] f32, e[K=512,C=256] f32.
// out[b,c,hw] = e[argmin_k ||z - e_k||^2][c].
//
// R8: 1-term bf16 MFMA main pass (score_k ~= ||e_k||^2 - 2 zh.eh, pair-error
// sigma ~0.06, EPS=0.6 ~ 10 sigma) tracking TOP-3 scores + top-2 indices.
// Flagged rows split:
//   gap12 < EPS <= gap13  -> pair_refine: exact fp64 compare of {bidx,sidx}
//   gap13 < EPS           -> full_refine: exact fp64 scan of all 512 codes
// (R7's single full-scan refine was 460us: 2048-deep dependent fp64 chains +
// uncoalesced e walks over ~6.5k jobs. Pair jobs are O(2 codes) instead.)

typedef __attribute__((ext_vector_type(8))) short bf16x8;
typedef __attribute__((ext_vector_type(4))) float f32x4;

constexpr int K_EMB = 512;
constexpr int C_DIM = 256;
constexpr int HW    = 1024;
constexpr float EPS_GAP = 0.6f;

// ws layout (bytes)
constexpr size_t WS_EBIAS = 64;                    // f32[512]
constexpr size_t WS_EH    = 4096;                  // bf16 bits [512][256] = 256KB
constexpr size_t WS_PAIR  = WS_EH + 262144;        // pair jobs: 2 ints each

// LDS (main): 3 x 8KB e-tile buffers | ebias f32[512] | idx int[128]
constexpr int LDS_TILES = 24576;
constexpr int LDS_EB    = LDS_TILES;           // +2048
constexpr int LDS_IDX   = LDS_TILES + 2048;    // +512 -> 27136 total

__device__ __forceinline__ unsigned short f2bf(float f) {
    unsigned u = __float_as_uint(f);
    return (unsigned short)((u + 0x7FFFu + ((u >> 16) & 1u)) >> 16);
}

// ---- prep: e -> eH bf16 plane + exact ebias, zero job counters ----
__global__ __launch_bounds__(256) void prep_e(const float* __restrict__ e,
                                              unsigned short* __restrict__ eH,
                                              float* __restrict__ ebias,
                                              int* __restrict__ count) {
    const int k = blockIdx.x, c = threadIdx.x;
    if (k == 0 && c < 2) count[c] = 0;
    float v = e[(size_t)k * C_DIM + c];
    eH[(size_t)k * C_DIM + c] = f2bf(v);

    __shared__ double red[256];
    red[c] = (double)v * (double)v;
    __syncthreads();
    for (int s = 128; s > 0; s >>= 1) {
        if (c < s) red[c] += red[c + s];
        __syncthreads();
    }
    if (c == 0) ebias[k] = (float)red[0];
}

// ---- stage one 16-code e-tile (8KB) into LDS at bufoff ----
// global_load_lds: wave-uniform LDS base, lane*16 contiguous. Bank-conflict
// swizzle (byte ^= (row&15)<<4) applied on the GLOBAL source address;
// readers apply the same XOR. (R4-R7 verified.)
__device__ __forceinline__ void stage_tile(char* smem, int bufoff, int nt, int w, int lane,
                                           const unsigned short* eH) {
#pragma unroll
    for (int s = 0; s < 2; ++s) {
        int q = w * 2 + s;            // 0..7 across the block (1KB chunks)
        int row = q * 2 + (lane >> 5);
        int co  = (lane & 31) * 16;   // byte offset within 512B row
        const unsigned short* src = eH
            + ((size_t)(nt * 16 + row)) * C_DIM + ((co ^ ((row & 15) << 4)) >> 1);
        char* dst = smem + bufoff + q * 1024;  // wave-uniform
        __builtin_amdgcn_global_load_lds(
            (const __attribute__((address_space(1))) unsigned int*)src,
            (__attribute__((address_space(3))) unsigned int*)dst, 16, 0, 0);
    }
}

// ---- main: 1-term GEMM + in-register top-3 argmin + fused output gather ----
__global__ __launch_bounds__(256, 3) void vq_mfma(const float* __restrict__ x,
                                                  const unsigned short* __restrict__ eH,
                                                  const float* __restrict__ ebias,
                                                  const float* __restrict__ e,
                                                  float* __restrict__ out,
                                                  int* __restrict__ count,
                                                  int* __restrict__ pairlist,
                                                  int paircap,
                                                  int* __restrict__ fulllist,
                                                  int fullcap) {
    __shared__ __align__(16) char smem[LDS_IDX + 512];
    float* eb_lds = (float*)(smem + LDS_EB);
    int* idx_lds  = (int*)(smem + LDS_IDX);
    const int t = threadIdx.x, lane = t & 63, w = t >> 6;
    const int b = blockIdx.x >> 3;
    const int hw0 = (blockIdx.x & 7) << 7;
    const float* xb = x + (size_t)b * C_DIM * HW;

    // ebias -> LDS (published by the nt=0 barrier)
    eb_lds[t]       = ebias[t];
    eb_lds[t + 256] = ebias[t + 256];

    // prefetch e-tiles 0,1 (issued before A-build so latency hides under it)
    stage_tile(smem, 0,    0, w, lane, eH);
    stage_tile(smem, 8192, 1, w, lane, eH);

    // A fragments (bf16 hi plane): lane holds A[m=lane&15][k=8*(lane>>4)+j]
    bf16x8 Ah[2][8];
#pragma unroll
    for (int mf = 0; mf < 2; ++mf) {
        const int hw = hw0 + w * 32 + mf * 16 + (lane & 15);
#pragma unroll
        for (int cs = 0; cs < 8; ++cs) {
#pragma unroll
            for (int j = 0; j < 8; ++j) {
                int c = cs * 32 + ((lane >> 4) << 3) + j;
                Ah[mf][cs][j] = (short)f2bf(xb[(size_t)c * HW + hw]);
            }
        }
    }

    float best[8], second[8], third[8];
    int bidx[8], sidx[8];
#pragma unroll
    for (int s = 0; s < 8; ++s) {
        best[s] = 1e30f; second[s] = 1e30f; third[s] = 1e30f;
        bidx[s] = K_EMB; sidx[s] = K_EMB;
    }

    // per-lane swizzled LDS read base: row = lane&15 (code), co = (lane>>4)*16
    const int bro = (lane & 15) * 512 + ((((lane >> 4) << 4)) ^ ((lane & 15) << 4));

    asm volatile("s_waitcnt lgkmcnt(0)" ::: "memory");

    int cur = 0;
#pragma unroll 1
    for (int nt = 0; nt < 32; ++nt) {
        // tile nt's 2 loads/wave complete; tile nt+1's 2 may stay in flight
        if (nt == 31) asm volatile("s_waitcnt vmcnt(0)" ::: "memory");
        else          asm volatile("s_waitcnt vmcnt(2)" ::: "memory");
        __builtin_amdgcn_s_barrier();
        asm volatile("" ::: "memory");

        if (nt < 30) {
            int nb = cur + 16384; if (nb >= LDS_TILES) nb -= LDS_TILES;
            stage_tile(smem, nb, nt + 2, w, lane, eH);
        }

        const char* base = smem + cur;
        f32x4 a0 = {0,0,0,0}, a1 = {0,0,0,0};
#pragma unroll
        for (int cs = 0; cs < 8; ++cs) {
            bf16x8 Bh = *reinterpret_cast<const bf16x8*>(base + (bro ^ (cs << 6)));
            a0 = __builtin_amdgcn_mfma_f32_16x16x32_bf16(Ah[0][cs], Bh, a0, 0, 0, 0);
            a1 = __builtin_amdgcn_mfma_f32_16x16x32_bf16(Ah[1][cs], Bh, a1, 0, 0, 0);
        }

        const int code = nt * 16 + (lane & 15);
        const float eb = eb_lds[code];
#pragma unroll
        for (int mf = 0; mf < 2; ++mf) {
#pragma unroll
            for (int r = 0; r < 4; ++r) {
                float sc = fmaf(-2.f, (mf ? a1[r] : a0[r]), eb);
                int s = mf * 4 + r;
                // codes ascend -> strict < gives first-index-wins
                if (sc < best[s]) {
                    third[s] = second[s]; second[s] = best[s]; sidx[s] = bidx[s];
                    best[s] = sc; bidx[s] = code;
                } else if (sc < second[s]) {
                    third[s] = second[s]; second[s] = sc; sidx[s] = code;
                } else if (sc < third[s]) {
                    third[s] = sc;
                }
            }
        }

        cur += 8192; if (cur == LDS_TILES) cur = 0;
    }

    // butterfly top-3 merge over the 16 col-lanes (lexicographic (score,idx))
#pragma unroll
    for (int m = 1; m < 16; m <<= 1) {
#pragma unroll
        for (int s = 0; s < 8; ++s) {
            float ob = __shfl_xor(best[s], m);
            float os = __shfl_xor(second[s], m);
            float ot = __shfl_xor(third[s], m);
            int   oi = __shfl_xor(bidx[s], m);
            int   oj = __shfl_xor(sidx[s], m);
            bool ltAB = ob < best[s] || (ob == best[s] && oi < bidx[s]);
            float wB = ltAB ? ob : best[s];   int wI = ltAB ? oi : bidx[s];
            float wS = ltAB ? os : second[s]; int wJ = ltAB ? oj : sidx[s];
            float wT = ltAB ? ot : third[s];
            float lB = ltAB ? best[s] : ob;   int lI = ltAB ? bidx[s] : oi;
            float lS = ltAB ? second[s] : os;
            bool lt2 = wS < lB || (wS == lB && wJ < lI);
            best[s]   = wB;  bidx[s] = wI;
            second[s] = lt2 ? wS : lB;
            sidx[s]   = lt2 ? wJ : lI;
            third[s]  = lt2 ? fminf(lB, wT) : fminf(wS, lS);
        }
    }

    if ((lane & 15) == 0) {
#pragma unroll
        for (int s = 0; s < 8; ++s) {
            int row_local = (s >> 2) * 16 + ((lane >> 4) << 2) + (s & 3);
            int r = w * 32 + row_local;
            idx_lds[r] = bidx[s];
            int row = blockIdx.x * 128 + r;
            if (third[s] - best[s] < EPS_GAP) {          // >=3 candidates: full scan
                int sl = atomicAdd(count + 1, 1);
                if (sl < fullcap) fulllist[sl] = row;
            } else if (second[s] - best[s] < EPS_GAP) {  // 2 candidates: pair job
                int sl = atomicAdd(count, 1);
                if (sl < paircap) {
                    pairlist[2 * sl]     = row;
                    pairlist[2 * sl + 1] = (bidx[s] << 16) | sidx[s];
                }
            }
        }
    }
    __syncthreads();

    // fused gather: out[b,c,hw] = e[idx[j]][c]
    {
        const int j = t & 127;
        const int half = t >> 7;
        const int code = idx_lds[j];
        const float4* e4 = reinterpret_cast<const float4*>(e);
        float* ob = out + (size_t)b * C_DIM * HW + hw0 + j;
#pragma unroll
        for (int i = 0; i < 32; ++i) {
            int c4 = half * 32 + i;
            float4 v = e4[(size_t)code * 64 + c4];
            ob[(size_t)(c4 * 4 + 0) * HW] = v.x;
            ob[(size_t)(c4 * 4 + 1) * HW] = v.y;
            ob[(size_t)(c4 * 4 + 2) * HW] = v.z;
            ob[(size_t)(c4 * 4 + 3) * HW] = v.w;
        }
    }
}

// ---- pair_refine: exact fp64 compare of 2 candidate codes; 4 jobs/block ----
__global__ __launch_bounds__(256) void pair_refine(const float* __restrict__ x,
                                                   const float* __restrict__ e,
                                                   float* __restrict__ out,
                                                   const int* __restrict__ pairlist,
                                                   const int* __restrict__ count,
                                                   int paircap) {
    int njobs = count[0]; if (njobs > paircap) njobs = paircap;
    const int lane = threadIdx.x & 63, w = threadIdx.x >> 6;

    for (int job = blockIdx.x * 4 + w; job < njobs; job += gridDim.x * 4) {
        const int row = pairlist[2 * job];
        const int ab  = pairlist[2 * job + 1];
        const int a = ab >> 16, b2 = ab & 0xffff;
        const float* xb = x + (size_t)(row >> 10) * (C_DIM * HW) + (row & 1023);

        const float4 ea = reinterpret_cast<const float4*>(e + (size_t)a  * C_DIM)[lane];
        const float4 eb = reinterpret_cast<const float4*>(e + (size_t)b2 * C_DIM)[lane];
        float z0 = xb[(size_t)(lane * 4 + 0) * HW];
        float z1 = xb[(size_t)(lane * 4 + 1) * HW];
        float z2 = xb[(size_t)(lane * 4 + 2) * HW];
        float z3 = xb[(size_t)(lane * 4 + 3) * HW];

        double da = 0.0, db = 0.0, df;
        df = (double)z0 - ea.x; da = fma(df, df, da);
        df = (double)z1 - ea.y; da = fma(df, df, da);
        df = (double)z2 - ea.z; da = fma(df, df, da);
        df = (double)z3 - ea.w; da = fma(df, df, da);
        df = (double)z0 - eb.x; db = fma(df, df, db);
        df = (double)z1 - eb.y; db = fma(df, df, db);
        df = (double)z2 - eb.z; db = fma(df, df, db);
        df = (double)z3 - eb.w; db = fma(df, df, db);
#pragma unroll
        for (int off = 1; off < 64; off <<= 1) {
            da += __shfl_xor(da, off);
            db += __shfl_xor(db, off);
        }
        const int winner = (da < db || (da == db && a < b2)) ? a : b2;
        if (winner != a) {   // vq already wrote e[a]; rewrite only on flip
            const float4 ew = reinterpret_cast<const float4*>(e + (size_t)winner * C_DIM)[lane];
            float* ob = out + (size_t)(row >> 10) * (C_DIM * HW) + (row & 1023);
            ob[(size_t)(lane * 4 + 0) * HW] = ew.x;
            ob[(size_t)(lane * 4 + 1) * HW] = ew.y;
            ob[(size_t)(lane * 4 + 2) * HW] = ew.z;
            ob[(size_t)(lane * 4 + 3) * HW] = ew.w;
        }
    }
}

// ---- full_refine: exact fp64 scan of all 512 codes (rare); 1 wave/block ----
__global__ __launch_bounds__(64) void full_refine(const float* __restrict__ x,
                                                  const float* __restrict__ e,
                                                  float* __restrict__ out,
                                                  const int* __restrict__ fulllist,
                                                  const int* __restrict__ count,
                                                  int fullcap) {
    __shared__ float zs[C_DIM];
    int njobs = count[1]; if (njobs > fullcap) njobs = fullcap;
    const int lane = threadIdx.x;

    for (int job = blockIdx.x; job < njobs; job += gridDim.x) {
        const int row = fulllist[job];
        const float* xb = x + (size_t)(row >> 10) * (C_DIM * HW) + (row & 1023);
#pragma unroll
        for (int i = 0; i < 4; ++i) {
            int c = lane + 64 * i;
            zs[c] = xb[(size_t)c * HW];
        }
        __syncthreads();

        double d[8];
#pragma unroll
        for (int i = 0; i < 8; ++i) d[i] = 0.0;
#pragma unroll 2
        for (int c4 = 0; c4 < 64; ++c4) {
            const float4 z4 = reinterpret_cast<const float4*>(zs)[c4];
#pragma unroll
            for (int i = 0; i < 8; ++i) {   // 8 independent fp64 chains
                const float4 ev = reinterpret_cast<const float4*>(
                    e + (size_t)(lane + 64 * i) * C_DIM)[c4];
                double df;
                df = (double)z4.x - ev.x; d[i] = fma(df, df, d[i]);
                df = (double)z4.y - ev.y; d[i] = fma(df, df, d[i]);
                df = (double)z4.z - ev.z; d[i] = fma(df, df, d[i]);
                df = (double)z4.w - ev.w; d[i] = fma(df, df, d[i]);
            }
        }
        double bd = d[0]; int bk = lane;
#pragma unroll
        for (int i = 1; i < 8; ++i)
            if (d[i] < bd) { bd = d[i]; bk = lane + 64 * i; }  // k ascends per lane
#pragma unroll
        for (int off = 1; off < 64; off <<= 1) {
            double od = __shfl_xor(bd, off);
            int    ok = __shfl_xor(bk, off);
            if (od < bd || (od == bd && ok < bk)) { bd = od; bk = ok; }
        }
        const float4 ew = reinterpret_cast<const float4*>(e + (size_t)bk * C_DIM)[lane];
        float* ob = out + (size_t)(row >> 10) * (C_DIM * HW) + (row & 1023);
        ob[(size_t)(lane * 4 + 0) * HW] = ew.x;
        ob[(size_t)(lane * 4 + 1) * HW] = ew.y;
        ob[(size_t)(lane * 4 + 2) * HW] = ew.z;
        ob[(size_t)(lane * 4 + 3) * HW] = ew.w;
        __syncthreads();
    }
}

extern "C" void kernel_launch(void* const* d_in, const int* in_sizes, int n_in,
                              void* d_out, int out_size, void* d_ws, size_t ws_size,
                              hipStream_t stream) {
    const float* x = (const float*)d_in[0];
    const float* e = (const float*)d_in[1];
    float* out = (float*)d_out;

    char* ws = (char*)d_ws;
    int* count = (int*)ws;                       // [0]=pair, [1]=full
    float* ebias = (float*)(ws + WS_EBIAS);
    unsigned short* eH = (unsigned short*)(ws + WS_EH);
    int* pairlist = (int*)(ws + WS_PAIR);

    int paircap = 0, fullcap = 0;
    if (ws_size > WS_PAIR + 64) {
        size_t avail = ws_size - WS_PAIR;
        size_t pc = (avail * 2 / 3) / 8;         // 2 ints per pair job
        paircap = (int)(pc > 49152 ? 49152 : pc);
        size_t rem = avail - (size_t)paircap * 8;
        size_t fc = rem / 4;
        fullcap = (int)(fc > 16384 ? 16384 : fc);
    }
    int* fulllist = pairlist + 2 * (size_t)paircap;

    const int B = in_sizes[0] / (C_DIM * HW);

    hipLaunchKernelGGL(prep_e, dim3(K_EMB), dim3(256), 0, stream, e, eH, ebias, count);
    hipLaunchKernelGGL(vq_mfma, dim3(B * 8), dim3(256), 0, stream,
                       x, eH, ebias, e, out, count, pairlist, paircap, fulllist, fullcap);
    hipLaunchKernelGGL(pair_refine, dim3(2048), dim3(256), 0, stream,
                       x, e, out, pairlist, count, paircap);
    hipLaunchKernelGGL(full_refine, dim3(1024), dim3(64), 0, stream,
                       x, e, out, fulllist, count, fullcap);
}

// Round 9
// 281.371 us; speedup vs baseline: 2.0484x; 1.3593x over previous
//
#include <hip/hip_runtime.h>

// VQ-VAE quantizer via MFMA: x[B=128,C=256,H=32,W=32] f32, e[K=512,C=256] f32.
// out[b,c,hw] = e[argmin_k ||z - e_k||^2][c].
//
// R9: the allocator squeezes VGPRs beyond launch_bounds (R5-R8: caps 128/84 =
// 512/4, 512/6) and rematerializes anything that doesn't fit -> VALU storms.
// Fix = make demand fit ANY squeeze:
//   - 16 rows/wave (Ah = 32 VGPR, 4 acc slots), 64 rows/block, 2048 blocks
//   - branchless top-3 via packed (score|code): 9 low mantissa bits carry the
//     code (score+4096 in one binade-pair, distortion <= 0.25, order-safe,
//     ties resolve to lower code). 3 floats/slot, pure min/max updates.
// Rows with packed gap12 < EPS=0.9 -> exact fp64 pair compare; gap13 < EPS ->
// exact fp64 full scan. (EPS = R7/R8's proven 0.6 + 0.25 packing distortion.)

typedef __attribute__((ext_vector_type(8))) short bf16x8;
typedef __attribute__((ext_vector_type(4))) float f32x4;

constexpr int K_EMB = 512;
constexpr int C_DIM = 256;
constexpr int HW    = 1024;
constexpr float EPS_GAP = 0.9f;

// ws layout (bytes)
constexpr size_t WS_EBIAS = 64;                    // f32[512] (= ||e_k||^2 + 4096)
constexpr size_t WS_EH    = 4096;                  // bf16 bits [512][256] = 256KB
constexpr size_t WS_PAIR  = WS_EH + 262144;        // pair jobs: 2 ints each

// LDS: 3 x 8KB e-tile buffers | ebias f32[512] | idx int[64]
constexpr int LDS_TILES = 24576;
constexpr int LDS_EB    = LDS_TILES;           // +2048
constexpr int LDS_IDX   = LDS_TILES + 2048;    // +256 -> 26880 total

__device__ __forceinline__ unsigned short f2bf(float f) {
    unsigned u = __float_as_uint(f);
    return (unsigned short)((u + 0x7FFFu + ((u >> 16) & 1u)) >> 16);
}

// med3 identity (no builtin dependency): median of 3
__device__ __forceinline__ float med3f(float a, float b, float c) {
    return fmaxf(fminf(a, b), fminf(fmaxf(a, b), c));
}

// ---- prep: e -> eH bf16 plane + (||e||^2 + 4096), zero job counters ----
__global__ __launch_bounds__(256) void prep_e(const float* __restrict__ e,
                                              unsigned short* __restrict__ eH,
                                              float* __restrict__ ebias,
                                              int* __restrict__ count) {
    const int k = blockIdx.x, c = threadIdx.x;
    if (k == 0 && c < 2) count[c] = 0;
    float v = e[(size_t)k * C_DIM + c];
    eH[(size_t)k * C_DIM + c] = f2bf(v);

    __shared__ double red[256];
    red[c] = (double)v * (double)v;
    __syncthreads();
    for (int s = 128; s > 0; s >>= 1) {
        if (c < s) red[c] += red[c + s];
        __syncthreads();
    }
    if (c == 0) ebias[k] = (float)red[0] + 4096.0f;   // bias keeps packed score positive, one binade-pair
}

// ---- stage one 16-code e-tile (8KB) into LDS at bufoff ----
// global_load_lds: wave-uniform LDS base, lane*16 contiguous. Bank-conflict
// swizzle (byte ^= (row&15)<<4) applied on the GLOBAL source address;
// readers apply the same XOR. (R4-R8 verified.)
__device__ __forceinline__ void stage_tile(char* smem, int bufoff, int nt, int w, int lane,
                                           const unsigned short* eH) {
#pragma unroll
    for (int s = 0; s < 2; ++s) {
        int q = w * 2 + s;            // 0..7 across the block (1KB chunks)
        int row = q * 2 + (lane >> 5);
        int co  = (lane & 31) * 16;   // byte offset within 512B row
        const unsigned short* src = eH
            + ((size_t)(nt * 16 + row)) * C_DIM + ((co ^ ((row & 15) << 4)) >> 1);
        char* dst = smem + bufoff + q * 1024;  // wave-uniform
        __builtin_amdgcn_global_load_lds(
            (const __attribute__((address_space(1))) unsigned int*)src,
            (__attribute__((address_space(3))) unsigned int*)dst, 16, 0, 0);
    }
}

// ---- main: 1-term GEMM + packed branchless top-3 + fused output gather ----
__global__ __launch_bounds__(256, 3) void vq_mfma(const float* __restrict__ x,
                                                  const unsigned short* __restrict__ eH,
                                                  const float* __restrict__ ebias,
                                                  const float* __restrict__ e,
                                                  float* __restrict__ out,
                                                  int* __restrict__ count,
                                                  int* __restrict__ pairlist,
                                                  int paircap,
                                                  int* __restrict__ fulllist,
                                                  int fullcap) {
    __shared__ __align__(16) char smem[LDS_IDX + 256];
    float* eb_lds = (float*)(smem + LDS_EB);
    int* idx_lds  = (int*)(smem + LDS_IDX);
    const int t = threadIdx.x, lane = t & 63, w = t >> 6;
    const int b = blockIdx.x >> 4;
    const int hw0 = (blockIdx.x & 15) << 6;
    const float* xb = x + (size_t)b * C_DIM * HW;

    // ebias -> LDS (published by the nt=0 barrier)
    eb_lds[t]       = ebias[t];
    eb_lds[t + 256] = ebias[t + 256];

    // prefetch e-tiles 0,1 (latency hides under A-build)
    stage_tile(smem, 0,    0, w, lane, eH);
    stage_tile(smem, 8192, 1, w, lane, eH);

    // A fragment (one 16-row m-frag): lane holds A[m=lane&15][k=8*(lane>>4)+j]
    bf16x8 Ah[8];
    {
        const int hw = hw0 + w * 16 + (lane & 15);
#pragma unroll
        for (int cs = 0; cs < 8; ++cs) {
#pragma unroll
            for (int j = 0; j < 8; ++j) {
                int c = cs * 32 + ((lane >> 4) << 3) + j;
                Ah[cs][j] = (short)f2bf(xb[(size_t)c * HW + hw]);
            }
        }
    }

    // packed top-3 per slot: t1 <= t2 <= t3, low 9 bits = code
    float t1[4], t2[4], t3[4];
#pragma unroll
    for (int r = 0; r < 4; ++r) { t1[r] = 1e30f; t2[r] = 1e30f; t3[r] = 1e30f; }

    // per-lane swizzled LDS read base: row = lane&15 (code), co = (lane>>4)*16
    const int bro = (lane & 15) * 512 + ((((lane >> 4) << 4)) ^ ((lane & 15) << 4));

    asm volatile("s_waitcnt lgkmcnt(0)" ::: "memory");

    int cur = 0;
#pragma unroll 1
    for (int nt = 0; nt < 32; ++nt) {
        // tile nt's 2 loads/wave complete; tile nt+1's 2 may stay in flight
        if (nt == 31) asm volatile("s_waitcnt vmcnt(0)" ::: "memory");
        else          asm volatile("s_waitcnt vmcnt(2)" ::: "memory");
        __builtin_amdgcn_s_barrier();
        asm volatile("" ::: "memory");

        if (nt < 30) {
            int nb = cur + 16384; if (nb >= LDS_TILES) nb -= LDS_TILES;
            stage_tile(smem, nb, nt + 2, w, lane, eH);
        }

        const char* base = smem + cur;
        f32x4 a0 = {0, 0, 0, 0};
#pragma unroll
        for (int cs = 0; cs < 8; ++cs) {
            bf16x8 Bh = *reinterpret_cast<const bf16x8*>(base + (bro ^ (cs << 6)));
            a0 = __builtin_amdgcn_mfma_f32_16x16x32_bf16(Ah[cs], Bh, a0, 0, 0, 0);
        }

        const int code = nt * 16 + (lane & 15);
        const float eb = eb_lds[code];   // = ||e||^2 + 4096
#pragma unroll
        for (int r = 0; r < 4; ++r) {
            float sc = fmaf(-2.f, a0[r], eb);               // in (2048, 8192)
            float sp = __uint_as_float((__float_as_uint(sc) & ~511u) | (unsigned)code);
            t3[r] = fminf(t3[r], fmaxf(t2[r], sp));          // sorted insert,
            t2[r] = fminf(fmaxf(sp, t1[r]), t2[r]);          // branchless
            t1[r] = fminf(t1[r], sp);
        }

        cur += 8192; if (cur == LDS_TILES) cur = 0;
    }

    // butterfly top-3 merge over the 16 col-lanes (packed => lexicographic)
#pragma unroll
    for (int m = 1; m < 16; m <<= 1) {
#pragma unroll
        for (int r = 0; r < 4; ++r) {
            float d  = __shfl_xor(t1[r], m);
            float e_ = __shfl_xor(t2[r], m);
            float f  = __shfl_xor(t3[r], m);
            float x1 = fminf(t1[r], d), y1 = fmaxf(t1[r], d);
            float x2 = fminf(t2[r], e_), y2 = fmaxf(t2[r], e_);
            float x3 = fminf(t3[r], f);
            t1[r] = x1;
            t2[r] = fminf(y1, x2);
            t3[r] = med3f(y1, x2, fminf(x3, y2));
        }
    }

    if ((lane & 15) == 0) {
#pragma unroll
        for (int r = 0; r < 4; ++r) {
            int row_local = w * 16 + ((lane >> 4) << 2) + r;
            int bcode = (int)(__float_as_uint(t1[r]) & 511u);
            idx_lds[row_local] = bcode;
            int row = blockIdx.x * 64 + row_local;            // = b*1024 + hw0 + row_local
            if (t3[r] - t1[r] < EPS_GAP) {                    // >=3 candidates: full scan
                int sl = atomicAdd(count + 1, 1);
                if (sl < fullcap) fulllist[sl] = row;
            } else if (t2[r] - t1[r] < EPS_GAP) {             // 2 candidates: pair job
                int scode = (int)(__float_as_uint(t2[r]) & 511u);
                int sl = atomicAdd(count, 1);
                if (sl < paircap) {
                    pairlist[2 * sl]     = row;
                    pairlist[2 * sl + 1] = (bcode << 16) | scode;
                }
            }
        }
    }
    __syncthreads();

    // fused gather: out[b,c,hw] = e[idx[j]][c]; wave w covers c4 in [w*16,w*16+16)
    {
        const int j = t & 63;
        const int code = idx_lds[j];
        const float4* e4 = reinterpret_cast<const float4*>(e);
        float* ob = out + (size_t)b * C_DIM * HW + hw0 + j;
#pragma unroll
        for (int i = 0; i < 16; ++i) {
            int c4 = w * 16 + i;
            float4 v = e4[(size_t)code * 64 + c4];
            ob[(size_t)(c4 * 4 + 0) * HW] = v.x;
            ob[(size_t)(c4 * 4 + 1) * HW] = v.y;
            ob[(size_t)(c4 * 4 + 2) * HW] = v.z;
            ob[(size_t)(c4 * 4 + 3) * HW] = v.w;
        }
    }
}

// ---- pair_refine: exact fp64 compare of 2 candidate codes; 4 jobs/block ----
__global__ __launch_bounds__(256) void pair_refine(const float* __restrict__ x,
                                                   const float* __restrict__ e,
                                                   float* __restrict__ out,
                                                   const int* __restrict__ pairlist,
                                                   const int* __restrict__ count,
                                                   int paircap) {
    int njobs = count[0]; if (njobs > paircap) njobs = paircap;
    const int lane = threadIdx.x & 63, w = threadIdx.x >> 6;

    for (int job = blockIdx.x * 4 + w; job < njobs; job += gridDim.x * 4) {
        const int row = pairlist[2 * job];
        const int ab  = pairlist[2 * job + 1];
        const int a = ab >> 16, b2 = ab & 0xffff;
        const float* xb = x + (size_t)(row >> 10) * (C_DIM * HW) + (row & 1023);

        const float4 ea = reinterpret_cast<const float4*>(e + (size_t)a  * C_DIM)[lane];
        const float4 eb = reinterpret_cast<const float4*>(e + (size_t)b2 * C_DIM)[lane];
        float z0 = xb[(size_t)(lane * 4 + 0) * HW];
        float z1 = xb[(size_t)(lane * 4 + 1) * HW];
        float z2 = xb[(size_t)(lane * 4 + 2) * HW];
        float z3 = xb[(size_t)(lane * 4 + 3) * HW];

        double da = 0.0, db = 0.0, df;
        df = (double)z0 - ea.x; da = fma(df, df, da);
        df = (double)z1 - ea.y; da = fma(df, df, da);
        df = (double)z2 - ea.z; da = fma(df, df, da);
        df = (double)z3 - ea.w; da = fma(df, df, da);
        df = (double)z0 - eb.x; db = fma(df, df, db);
        df = (double)z1 - eb.y; db = fma(df, df, db);
        df = (double)z2 - eb.z; db = fma(df, df, db);
        df = (double)z3 - eb.w; db = fma(df, df, db);
#pragma unroll
        for (int off = 1; off < 64; off <<= 1) {
            da += __shfl_xor(da, off);
            db += __shfl_xor(db, off);
        }
        const int winner = (da < db || (da == db && a < b2)) ? a : b2;
        if (winner != a) {   // vq already wrote e[a]; rewrite only on flip
            const float4 ew = reinterpret_cast<const float4*>(e + (size_t)winner * C_DIM)[lane];
            float* ob = out + (size_t)(row >> 10) * (C_DIM * HW) + (row & 1023);
            ob[(size_t)(lane * 4 + 0) * HW] = ew.x;
            ob[(size_t)(lane * 4 + 1) * HW] = ew.y;
            ob[(size_t)(lane * 4 + 2) * HW] = ew.z;
            ob[(size_t)(lane * 4 + 3) * HW] = ew.w;
        }
    }
}

// ---- full_refine: exact fp64 scan of all 512 codes (rare); 1 wave/block ----
__global__ __launch_bounds__(64) void full_refine(const float* __restrict__ x,
                                                  const float* __restrict__ e,
                                                  float* __restrict__ out,
                                                  const int* __restrict__ fulllist,
                                                  const int* __restrict__ count,
                                                  int fullcap) {
    __shared__ float zs[C_DIM];
    int njobs = count[1]; if (njobs > fullcap) njobs = fullcap;
    const int lane = threadIdx.x;

    for (int job = blockIdx.x; job < njobs; job += gridDim.x) {
        const int row = fulllist[job];
        const float* xb = x + (size_t)(row >> 10) * (C_DIM * HW) + (row & 1023);
#pragma unroll
        for (int i = 0; i < 4; ++i) {
            int c = lane + 64 * i;
            zs[c] = xb[(size_t)c * HW];
        }
        __syncthreads();

        double d[8];
#pragma unroll
        for (int i = 0; i < 8; ++i) d[i] = 0.0;
#pragma unroll 2
        for (int c4 = 0; c4 < 64; ++c4) {
            const float4 z4 = reinterpret_cast<const float4*>(zs)[c4];
#pragma unroll
            for (int i = 0; i < 8; ++i) {   // 8 independent fp64 chains
                const float4 ev = reinterpret_cast<const float4*>(
                    e + (size_t)(lane + 64 * i) * C_DIM)[c4];
                double df;
                df = (double)z4.x - ev.x; d[i] = fma(df, df, d[i]);
                df = (double)z4.y - ev.y; d[i] = fma(df, df, d[i]);
                df = (double)z4.z - ev.z; d[i] = fma(df, df, d[i]);
                df = (double)z4.w - ev.w; d[i] = fma(df, df, d[i]);
            }
        }
        double bd = d[0]; int bk = lane;
#pragma unroll
        for (int i = 1; i < 8; ++i)
            if (d[i] < bd) { bd = d[i]; bk = lane + 64 * i; }  // k ascends per lane
#pragma unroll
        for (int off = 1; off < 64; off <<= 1) {
            double od = __shfl_xor(bd, off);
            int    ok = __shfl_xor(bk, off);
            if (od < bd || (od == bd && ok < bk)) { bd = od; bk = ok; }
        }
        const float4 ew = reinterpret_cast<const float4*>(e + (size_t)bk * C_DIM)[lane];
        float* ob = out + (size_t)(row >> 10) * (C_DIM * HW) + (row & 1023);
        ob[(size_t)(lane * 4 + 0) * HW] = ew.x;
        ob[(size_t)(lane * 4 + 1) * HW] = ew.y;
        ob[(size_t)(lane * 4 + 2) * HW] = ew.z;
        ob[(size_t)(lane * 4 + 3) * HW] = ew.w;
        __syncthreads();
    }
}

extern "C" void kernel_launch(void* const* d_in, const int* in_sizes, int n_in,
                              void* d_out, int out_size, void* d_ws, size_t ws_size,
                              hipStream_t stream) {
    const float* x = (const float*)d_in[0];
    const float* e = (const float*)d_in[1];
    float* out = (float*)d_out;

    char* ws = (char*)d_ws;
    int* count = (int*)ws;                       // [0]=pair, [1]=full
    float* ebias = (float*)(ws + WS_EBIAS);
    unsigned short* eH = (unsigned short*)(ws + WS_EH);
    int* pairlist = (int*)(ws + WS_PAIR);

    int paircap = 0, fullcap = 0;
    if (ws_size > WS_PAIR + 64) {
        size_t avail = ws_size - WS_PAIR;
        size_t pc = (avail * 2 / 3) / 8;         // 2 ints per pair job
        paircap = (int)(pc > 49152 ? 49152 : pc);
        size_t rem = avail - (size_t)paircap * 8;
        size_t fc = rem / 4;
        fullcap = (int)(fc > 16384 ? 16384 : fc);
    }
    int* fulllist = pairlist + 2 * (size_t)paircap;

    const int B = in_sizes[0] / (C_DIM * HW);

    hipLaunchKernelGGL(prep_e, dim3(K_EMB), dim3(256), 0, stream, e, eH, ebias, count);
    hipLaunchKernelGGL(vq_mfma, dim3(B * 16), dim3(256), 0, stream,
                       x, eH, ebias, e, out, count, pairlist, paircap, fulllist, fullcap);
    hipLaunchKernelGGL(pair_refine, dim3(2048), dim3(256), 0, stream,
                       x, e, out, pairlist, count, paircap);
    hipLaunchKernelGGL(full_refine, dim3(1024), dim3(64), 0, stream,
                       x, e, out, fulllist, count, fullcap);
}